// Round 10
// baseline (450.311 us; speedup 1.0000x reference)
//
#include <hip/hip_runtime.h>
#include <hip/hip_fp16.h>

#define NN 50000
#define NE 800000
#define FD 64
#define PD 20
#define NG 500
#define NXCD 8
#define DRANGE 6250            // NN / NXCD
#define CHUNK_E 2048

// ---------------- setup kernels ----------------

__global__ void k_deg_xcd(const int* __restrict__ dstA, int* __restrict__ deg) {
    int xcd = blockIdx.x & 7;
    int chunk = blockIdx.x >> 3;
    int lo = xcd * DRANGE;
    int hi = lo + DRANGE;
    int base = chunk * CHUNK_E;
    int end = min(base + CHUNK_E, NE);
    for (int i = base + threadIdx.x; i < end; i += 256) {
        int d = dstA[i];
        if (d >= lo && d < hi) atomicAdd(&deg[d], 1);
    }
}

// scan1 + dinv fused
__global__ void k_scan1(const int* __restrict__ deg, int* __restrict__ rowp,
                        int* __restrict__ bsum, float* __restrict__ dinv) {
    __shared__ int lds[256];
    int t = threadIdx.x;
    int idx = blockIdx.x * 256 + t;
    int v = (idx < NN) ? deg[idx] : 0;
    if (idx < NN) dinv[idx] = rsqrtf((float)v + 1.0f);
    lds[t] = v;
    __syncthreads();
    for (int off = 1; off < 256; off <<= 1) {
        int add = (t >= off) ? lds[t - off] : 0;
        __syncthreads();
        lds[t] += add;
        __syncthreads();
    }
    if (idx < NN) rowp[idx + 1] = lds[t];
    if (t == 255) bsum[blockIdx.x] = lds[255];
}

__global__ void k_scan2(int* bsum, int nB) {
    __shared__ int lds[256];
    int t = threadIdx.x;
    lds[t] = (t < nB) ? bsum[t] : 0;
    __syncthreads();
    for (int off = 1; off < 256; off <<= 1) {
        int add = (t >= off) ? lds[t - off] : 0;
        __syncthreads();
        lds[t] += add;
        __syncthreads();
    }
    if (t < nB) bsum[t] = lds[t];
}

__global__ void k_scan3(int* __restrict__ rowp, const int* __restrict__ bsum,
                        int* __restrict__ fill) {
    int idx = blockIdx.x * 256 + threadIdx.x;
    if (idx == 0) { rowp[0] = 0; fill[0] = 0; }
    if (idx < NN) {
        int v = rowp[idx + 1];
        if (blockIdx.x > 0) { v += bsum[blockIdx.x - 1]; rowp[idx + 1] = v; }
        if (idx + 1 < NN) fill[idx + 1] = v;
    }
}

__global__ void k_csr_fill_xcd(const int* __restrict__ srcA, const int* __restrict__ dstA,
                               const float* __restrict__ dinv,
                               int* __restrict__ fill, int2* __restrict__ meta) {
    int xcd = blockIdx.x & 7;
    int chunk = blockIdx.x >> 3;
    int lo = xcd * DRANGE;
    int hi = lo + DRANGE;
    int base = chunk * CHUNK_E;
    int end = min(base + CHUNK_E, NE);
    for (int i = base + threadIdx.x; i < end; i += 256) {
        int d = dstA[i];
        if (d >= lo && d < hi) {
            int s = srcA[i];
            int pos = atomicAdd(&fill[d], 1);
            int2 m;
            m.x = s;
            m.y = __float_as_int(dinv[s]);
            meta[pos] = m;
        }
    }
}

// ---------------- compute kernels ----------------

// pe = RWPE @ W_rw + b_rw ; writes interleaved fp16 row: [hs = x+pe | pe]
__global__ void k_pe(const float* __restrict__ x, const float* __restrict__ rwpe,
                     const float* __restrict__ Wrw, const float* __restrict__ brw,
                     __half* __restrict__ outI) {
    __shared__ float Wl[PD * FD];
    __shared__ float rows[4 * PD];
    int t = threadIdx.x;
    int nodeBase = blockIdx.x * 4;
    for (int i = t; i < PD * FD; i += 256) Wl[i] = Wrw[i];
    if (t < 4 * PD) {
        int n = nodeBase + t / PD;
        rows[t] = (n < NN) ? rwpe[n * PD + (t % PD)] : 0.f;
    }
    __syncthreads();
    int f = t & 63, sl = t >> 6;
    int node = nodeBase + sl;
    if (node < NN) {
        float acc = brw[f];
        #pragma unroll
        for (int k = 0; k < PD; k++) acc += rows[sl * PD + k] * Wl[k * FD + f];
        outI[(size_t)node * 128 + f]      = __float2half_rn(x[node * FD + f] + acc);
        outI[(size_t)node * 128 + 64 + f] = __float2half_rn(acc);
    }
}

__device__ inline void acc8(float* acc, uint4 v, float w) {
    const __half2* h = reinterpret_cast<const __half2*>(&v);
    float2 f0 = __half22float2(h[0]);
    float2 f1 = __half22float2(h[1]);
    float2 f2 = __half22float2(h[2]);
    float2 f3 = __half22float2(h[3]);
    acc[0] += w * f0.x; acc[1] += w * f0.y;
    acc[2] += w * f1.x; acc[3] += w * f1.y;
    acc[4] += w * f2.x; acc[5] += w * f2.y;
    acc[6] += w * f3.x; acc[7] += w * f3.y;
}

__device__ inline void acc4(float* acc, uint2 v, float w) {
    const __half2* h = reinterpret_cast<const __half2*>(&v);
    float2 f0 = __half22float2(h[0]);
    float2 f1 = __half22float2(h[1]);
    acc[0] += w * f0.x; acc[1] += w * f0.y;
    acc[2] += w * f1.x; acc[3] += w * f1.y;
}

// Fused dual GCN conv, 512 threads/block, 16 nodes, 32 lanes/node.
// Gather: 32-edge chunks, meta one coalesced load/lane, edges split even/odd
// between lane halves (2x concurrency, half the serial depth), partials
// combined via shfl_xor(16). GEMM-h (t<256) and GEMM-p (t>=256) concurrent.
template <bool FINAL>
__global__ __launch_bounds__(512) void k_dual(
    const __half* __restrict__ in,
    const float* __restrict__ dinv, const int* __restrict__ rowp,
    const int2* __restrict__ meta,
    const float* __restrict__ Wc, const float* __restrict__ bc,
    const float* __restrict__ Wp, const float* __restrict__ bp,
    __half* __restrict__ out, int write_pe,
    float* __restrict__ foutF)
{
    __shared__ float WcL[64 * 64];
    __shared__ float WpL[FINAL ? 4 : 64 * 64];
    __shared__ float aggH[16 * 68];
    __shared__ float aggP[FINAL ? 4 : 16 * 68];
    int t = threadIdx.x;

    // stage weights (1024 float4 each, 2 per thread)
    {
        const float4* W4 = reinterpret_cast<const float4*>(Wc);
        float4* WL4 = reinterpret_cast<float4*>(WcL);
        WL4[t] = W4[t];
        WL4[t + 512] = W4[t + 512];
        if (!FINAL) {
            const float4* P4 = reinterpret_cast<const float4*>(Wp);
            float4* PL4 = reinterpret_cast<float4*>(WpL);
            PL4[t] = P4[t];
            PL4[t + 512] = P4[t + 512];
        }
    }

    int sl = t >> 5;           // node slot 0..15
    int l32 = t & 31;          // lane within slot
    int half = l32 >> 4;       // edge parity handled by this lane
    int l = l32 & 15;          // 16B-chunk of the row
    int baseLane = (sl & 1) * 32;  // slot's base lane within its wave
    int node = blockIdx.x * 16 + sl;
    int e0 = rowp[node], e1 = rowp[node + 1];
    int cnt = e1 - e0;
    float dd = dinv[node];

    if (!FINAL) {
        const uint4* base = reinterpret_cast<const uint4*>(in);   // row = 16 uint4
        uint4 sv = base[(size_t)node * 16 + l];                   // self row (early)
        float acc[8] = {0, 0, 0, 0, 0, 0, 0, 0};
        for (int cb = 0; cb < cnt; cb += 32) {
            int midx = min(e0 + cb + l32, e1 - 1);
            int2 mreg = meta[midx];
            int rem = cnt - cb;
            int src0 = __shfl(mreg.x, baseLane, 64);
            #pragma unroll
            for (int g = 0; g < 2; g++) {
                if (g == 1 && rem <= 16) break;    // slot-uniform
                int srcj[8]; float wj[8];
                #pragma unroll
                for (int kk = 0; kk < 8; kk++) {
                    int j = 2 * (g * 8 + kk) + half;
                    int sx = __shfl(mreg.x, baseLane + j, 64);
                    float ww = __int_as_float(__shfl(mreg.y, baseLane + j, 64));
                    bool valid = (j < rem);
                    srcj[kk] = valid ? sx : src0;
                    wj[kk] = valid ? ww : 0.f;
                }
                uint4 v0 = base[(size_t)srcj[0] * 16 + l];
                uint4 v1 = base[(size_t)srcj[1] * 16 + l];
                uint4 v2 = base[(size_t)srcj[2] * 16 + l];
                uint4 v3 = base[(size_t)srcj[3] * 16 + l];
                uint4 v4 = base[(size_t)srcj[4] * 16 + l];
                uint4 v5 = base[(size_t)srcj[5] * 16 + l];
                uint4 v6 = base[(size_t)srcj[6] * 16 + l];
                uint4 v7 = base[(size_t)srcj[7] * 16 + l];
                acc8(acc, v0, wj[0]);
                acc8(acc, v1, wj[1]);
                acc8(acc, v2, wj[2]);
                acc8(acc, v3, wj[3]);
                acc8(acc, v4, wj[4]);
                acc8(acc, v5, wj[5]);
                acc8(acc, v6, wj[6]);
                acc8(acc, v7, wj[7]);
            }
        }
        // combine even/odd halves
        #pragma unroll
        for (int i = 0; i < 8; i++) acc[i] += __shfl_xor(acc[i], 16, 64);
        if (half == 0) {
            const __half2* h = reinterpret_cast<const __half2*>(&sv);
            float2 f0 = __half22float2(h[0]);
            float2 f1 = __half22float2(h[1]);
            float2 f2 = __half22float2(h[2]);
            float2 f3 = __half22float2(h[3]);
            float s[8] = {f0.x, f0.y, f1.x, f1.y, f2.x, f2.y, f3.x, f3.y};
            float* dst = (l < 8) ? &aggH[sl * 68 + l * 8] : &aggP[sl * 68 + (l - 8) * 8];
            float4* d4 = reinterpret_cast<float4*>(dst);
            d4[0] = make_float4(dd * acc[0] + dd * dd * s[0],
                                dd * acc[1] + dd * dd * s[1],
                                dd * acc[2] + dd * dd * s[2],
                                dd * acc[3] + dd * dd * s[3]);
            d4[1] = make_float4(dd * acc[4] + dd * dd * s[4],
                                dd * acc[5] + dd * dd * s[5],
                                dd * acc[6] + dd * dd * s[6],
                                dd * acc[7] + dd * dd * s[7]);
        }
    } else {
        const uint2* base2 = reinterpret_cast<const uint2*>(in);  // hs = first 16 uint2 of row
        uint2 sv = base2[(size_t)node * 32 + l];
        float acc[4] = {0, 0, 0, 0};
        for (int cb = 0; cb < cnt; cb += 32) {
            int midx = min(e0 + cb + l32, e1 - 1);
            int2 mreg = meta[midx];
            int rem = cnt - cb;
            int src0 = __shfl(mreg.x, baseLane, 64);
            #pragma unroll
            for (int g = 0; g < 2; g++) {
                if (g == 1 && rem <= 16) break;
                int srcj[8]; float wj[8];
                #pragma unroll
                for (int kk = 0; kk < 8; kk++) {
                    int j = 2 * (g * 8 + kk) + half;
                    int sx = __shfl(mreg.x, baseLane + j, 64);
                    float ww = __int_as_float(__shfl(mreg.y, baseLane + j, 64));
                    bool valid = (j < rem);
                    srcj[kk] = valid ? sx : src0;
                    wj[kk] = valid ? ww : 0.f;
                }
                uint2 v0 = base2[(size_t)srcj[0] * 32 + l];
                uint2 v1 = base2[(size_t)srcj[1] * 32 + l];
                uint2 v2 = base2[(size_t)srcj[2] * 32 + l];
                uint2 v3 = base2[(size_t)srcj[3] * 32 + l];
                uint2 v4 = base2[(size_t)srcj[4] * 32 + l];
                uint2 v5 = base2[(size_t)srcj[5] * 32 + l];
                uint2 v6 = base2[(size_t)srcj[6] * 32 + l];
                uint2 v7 = base2[(size_t)srcj[7] * 32 + l];
                acc4(acc, v0, wj[0]);
                acc4(acc, v1, wj[1]);
                acc4(acc, v2, wj[2]);
                acc4(acc, v3, wj[3]);
                acc4(acc, v4, wj[4]);
                acc4(acc, v5, wj[5]);
                acc4(acc, v6, wj[6]);
                acc4(acc, v7, wj[7]);
            }
        }
        #pragma unroll
        for (int i = 0; i < 4; i++) acc[i] += __shfl_xor(acc[i], 16, 64);
        if (half == 0) {
            const __half2* h = reinterpret_cast<const __half2*>(&sv);
            float2 f0 = __half22float2(h[0]);
            float2 f1 = __half22float2(h[1]);
            float s[4] = {f0.x, f0.y, f1.x, f1.y};
            float4* d4 = reinterpret_cast<float4*>(&aggH[sl * 68 + l * 4]);
            d4[0] = make_float4(dd * acc[0] + dd * dd * s[0],
                                dd * acc[1] + dd * dd * s[1],
                                dd * acc[2] + dd * dd * s[2],
                                dd * acc[3] + dd * dd * s[3]);
        }
    }
    __syncthreads();

    // concurrent GEMMs: t<256 -> h-conv, t>=256 -> pe-conv
    int c = t & 15;
    int sl2 = (t >> 4) & 15;
    int onode = blockIdx.x * 16 + sl2;
    float4 oh = make_float4(0.f, 0.f, 0.f, 0.f);
    float4 op = make_float4(0.f, 0.f, 0.f, 0.f);
    if (t < 256) {
        oh = *reinterpret_cast<const float4*>(bc + c * 4);
        const float* arow = &aggH[sl2 * 68];
        #pragma unroll 16
        for (int k = 0; k < 64; k++) {
            float av = arow[k];
            float4 wv = *reinterpret_cast<const float4*>(&WcL[k * 64 + c * 4]);
            oh.x += av * wv.x; oh.y += av * wv.y; oh.z += av * wv.z; oh.w += av * wv.w;
        }
        if (FINAL) {
            *reinterpret_cast<float4*>(foutF + (size_t)onode * 64 + c * 4) = oh;
        }
    } else if (!FINAL) {
        op = *reinterpret_cast<const float4*>(bp + c * 4);
        const float* arow = &aggP[sl2 * 68];
        #pragma unroll 16
        for (int k = 0; k < 64; k++) {
            float av = arow[k];
            float4 wv = *reinterpret_cast<const float4*>(&WpL[k * 64 + c * 4]);
            op.x += av * wv.x; op.y += av * wv.y; op.z += av * wv.z; op.w += av * wv.w;
        }
        op.x = fmaxf(op.x, 0.f); op.y = fmaxf(op.y, 0.f);
        op.z = fmaxf(op.z, 0.f); op.w = fmaxf(op.w, 0.f);
    }
    if (FINAL) return;

    __syncthreads();   // aggH free now
    uint2* out2 = reinterpret_cast<uint2*>(out);
    if (t >= 256) {
        // pass op to h-threads through aggH; write pe_out
        *reinterpret_cast<float4*>(&aggH[sl2 * 68 + c * 4]) = op;
        if (write_pe) {
            __half2 a = __floats2half2_rn(op.x, op.y);
            __half2 b = __floats2half2_rn(op.z, op.w);
            uint2 u;
            u.x = *reinterpret_cast<unsigned int*>(&a);
            u.y = *reinterpret_cast<unsigned int*>(&b);
            out2[(size_t)onode * 32 + 16 + c] = u;
        }
    }
    __syncthreads();
    if (t < 256) {
        oh.x = fmaxf(oh.x, 0.f); oh.y = fmaxf(oh.y, 0.f);
        oh.z = fmaxf(oh.z, 0.f); oh.w = fmaxf(oh.w, 0.f);
        float4 opv = *reinterpret_cast<const float4*>(&aggH[sl2 * 68 + c * 4]);
        __half2 a = __floats2half2_rn(oh.x + opv.x, oh.y + opv.y);
        __half2 b = __floats2half2_rn(oh.z + opv.z, oh.w + opv.w);
        uint2 u;
        u.x = *reinterpret_cast<unsigned int*>(&a);
        u.y = *reinterpret_cast<unsigned int*>(&b);
        out2[(size_t)onode * 32 + c] = u;
    }
}

// ---------------- batchnorm + pool ----------------

__global__ void k_bnstats(const float* __restrict__ h, float* __restrict__ stats) {
    __shared__ float s1[256], s2[256];
    int t = threadIdx.x;
    int f = t & 63, sl = t >> 6;
    float a = 0.f, b = 0.f;
    for (int node = blockIdx.x * 4 + sl; node < NN; node += gridDim.x * 4) {
        float v = h[node * 64 + f];
        a += v;
        b += v * v;
    }
    s1[t] = a;
    s2[t] = b;
    __syncthreads();
    if (t < 64) {
        a = s1[t] + s1[t + 64] + s1[t + 128] + s1[t + 192];
        b = s2[t] + s2[t + 64] + s2[t + 128] + s2[t + 192];
        atomicAdd(&stats[t], a);
        atomicAdd(&stats[64 + t], b);
    }
}

__global__ void k_bnfinal(float* stats) {
    int f = threadIdx.x;
    if (f < 64) {
        float mu = stats[f] / (float)NN;
        float var = stats[64 + f] / (float)NN - mu * mu;
        stats[f] = mu;
        stats[64 + f] = rsqrtf(var + 1e-5f);
    }
}

__global__ void k_pool(const float* __restrict__ h, const float* __restrict__ stats,
                       const float* __restrict__ gamma, const float* __restrict__ beta,
                       const int* __restrict__ ptr, float* __restrict__ out) {
    int g = blockIdx.x;
    int f = threadIdx.x;
    int s = ptr[g], e = ptr[g + 1];
    float mu = stats[f], rstd = stats[64 + f], ga = gamma[f], be = beta[f];
    float acc = 0.f;
    for (int n = s; n < e; n++) {
        float v = (h[n * 64 + f] - mu) * rstd * ga + be;
        acc += fmaxf(v, 0.f);
    }
    out[g * 64 + f] = acc / (float)(e - s);
}

// ---------------- launch ----------------

extern "C" void kernel_launch(void* const* d_in, const int* in_sizes, int n_in,
                              void* d_out, int out_size, void* d_ws, size_t ws_size,
                              hipStream_t stream) {
    const float* x    = (const float*)d_in[0];
    const float* rwpe = (const float*)d_in[1];
    const float* Wrw  = (const float*)d_in[2];
    const float* brw  = (const float*)d_in[3];
    const float *Wc[5], *bc[5], *Wp[5], *bp[5];
    for (int i = 0; i < 5; i++) {
        Wc[i] = (const float*)d_in[4 + 4 * i];
        bc[i] = (const float*)d_in[5 + 4 * i];
        Wp[i] = (const float*)d_in[6 + 4 * i];
        bp[i] = (const float*)d_in[7 + 4 * i];
    }
    const float* gamma = (const float*)d_in[24];
    const float* beta  = (const float*)d_in[25];
    const int* ei  = (const int*)d_in[26];
    const int* ptr = (const int*)d_in[27];
    float* out = (float*)d_out;

    char* wsp = (char*)d_ws;
    auto alloc = [&](size_t bytes) { void* p = (void*)wsp; wsp += ((bytes + 255) / 256) * 256; return p; };
    int*    deg   = (int*)alloc(NN * 4);
    int*    rowp  = (int*)alloc((NN + 1) * 4);
    int*    fill  = (int*)alloc(NN * 4);
    int2*   meta  = (int2*)alloc((size_t)NE * 8);
    float*  dinv  = (float*)alloc(NN * 4);
    __half* bufP  = (__half*)alloc((size_t)NN * 128 * 2);   // interleaved [hs|pe]
    __half* bufQ  = (__half*)alloc((size_t)NN * 128 * 2);
    float*  bufF  = (float*)alloc((size_t)NN * 64 * 4);     // final conv5 out fp32
    float*  stats = (float*)alloc(512);
    int*    bsum  = (int*)alloc(256 * 4);

    hipMemsetAsync(deg, 0, NN * 4, stream);
    hipMemsetAsync(stats, 0, 512, stream);

    const int* srcA = ei;
    const int* dstA = ei + NE;

    dim3 b256(256);
    dim3 b512(512);
    int gN = (NN + 255) / 256;
    int gNode16 = NN / 16;                            // 3125 (exact)
    int gFill = ((NE + CHUNK_E - 1) / CHUNK_E) * 8;   // 391 * 8 = 3128

    k_deg_xcd<<<gFill, b256, 0, stream>>>(dstA, deg);
    k_scan1<<<gN, b256, 0, stream>>>(deg, rowp, bsum, dinv);
    k_scan2<<<1, b256, 0, stream>>>(bsum, gN);
    k_scan3<<<gN, b256, 0, stream>>>(rowp, bsum, fill);
    k_csr_fill_xcd<<<gFill, b256, 0, stream>>>(srcA, dstA, dinv, fill, meta);

    k_pe<<<(NN + 3) / 4, b256, 0, stream>>>(x, rwpe, Wrw, brw, bufP);

    // K0..K3: dual convs; K3 skips dead pe write
    k_dual<false><<<gNode16, b512, 0, stream>>>(
        bufP, dinv, rowp, meta, Wc[0], bc[0], Wp[0], bp[0], bufQ, 1, nullptr);
    k_dual<false><<<gNode16, b512, 0, stream>>>(
        bufQ, dinv, rowp, meta, Wc[1], bc[1], Wp[1], bp[1], bufP, 1, nullptr);
    k_dual<false><<<gNode16, b512, 0, stream>>>(
        bufP, dinv, rowp, meta, Wc[2], bc[2], Wp[2], bp[2], bufQ, 1, nullptr);
    k_dual<false><<<gNode16, b512, 0, stream>>>(
        bufQ, dinv, rowp, meta, Wc[3], bc[3], Wp[3], bp[3], bufP, 0, nullptr);
    // K4: final conv (hs only) -> fp32
    k_dual<true><<<gNode16, b512, 0, stream>>>(
        bufP, dinv, rowp, meta, Wc[4], bc[4], nullptr, nullptr, nullptr, 0, bufF);

    k_bnstats<<<256, b256, 0, stream>>>(bufF, stats);
    k_bnfinal<<<1, 64, 0, stream>>>(stats);
    k_pool<<<NG, 64, 0, stream>>>(bufF, stats, gamma, beta, ptr, out);
}

// Round 11
// 363.938 us; speedup vs baseline: 1.2373x; 1.2373x over previous
//
#include <hip/hip_runtime.h>
#include <hip/hip_fp16.h>

#define NN 50000
#define NE 800000
#define FD 64
#define PD 20
#define NG 500
#define NXCD 8
#define DRANGE 6250            // NN / NXCD
#define CHUNK_E 2048

// ---------------- setup kernels ----------------

__global__ void k_deg_xcd(const int* __restrict__ dstA, int* __restrict__ deg) {
    int xcd = blockIdx.x & 7;
    int chunk = blockIdx.x >> 3;
    int lo = xcd * DRANGE;
    int hi = lo + DRANGE;
    int base = chunk * CHUNK_E;
    int end = min(base + CHUNK_E, NE);
    for (int i = base + threadIdx.x; i < end; i += 256) {
        int d = dstA[i];
        if (d >= lo && d < hi) atomicAdd(&deg[d], 1);
    }
}

// scan1 + dinv fused
__global__ void k_scan1(const int* __restrict__ deg, int* __restrict__ rowp,
                        int* __restrict__ bsum, float* __restrict__ dinv) {
    __shared__ int lds[256];
    int t = threadIdx.x;
    int idx = blockIdx.x * 256 + t;
    int v = (idx < NN) ? deg[idx] : 0;
    if (idx < NN) dinv[idx] = rsqrtf((float)v + 1.0f);
    lds[t] = v;
    __syncthreads();
    for (int off = 1; off < 256; off <<= 1) {
        int add = (t >= off) ? lds[t - off] : 0;
        __syncthreads();
        lds[t] += add;
        __syncthreads();
    }
    if (idx < NN) rowp[idx + 1] = lds[t];
    if (t == 255) bsum[blockIdx.x] = lds[255];
}

// finalize rowp AND fill[] ; each block redundantly scans bsum in LDS (no scan2 kernel)
__global__ void k_scan3(int* __restrict__ rowp, const int* __restrict__ bsum,
                        int* __restrict__ fill, int nB) {
    __shared__ int lds[256];
    int t = threadIdx.x;
    lds[t] = (t < nB) ? bsum[t] : 0;
    __syncthreads();
    for (int off = 1; off < 256; off <<= 1) {
        int add = (t >= off) ? lds[t - off] : 0;
        __syncthreads();
        lds[t] += add;
        __syncthreads();
    }
    int addv = (blockIdx.x > 0) ? lds[blockIdx.x - 1] : 0;
    int idx = blockIdx.x * 256 + t;
    if (idx == 0) { rowp[0] = 0; fill[0] = 0; }
    if (idx < NN) {
        int v = rowp[idx + 1] + addv;
        rowp[idx + 1] = v;
        if (idx + 1 < NN) fill[idx + 1] = v;
    }
}

__global__ void k_csr_fill_xcd(const int* __restrict__ srcA, const int* __restrict__ dstA,
                               const float* __restrict__ dinv,
                               int* __restrict__ fill, int2* __restrict__ meta) {
    int xcd = blockIdx.x & 7;
    int chunk = blockIdx.x >> 3;
    int lo = xcd * DRANGE;
    int hi = lo + DRANGE;
    int base = chunk * CHUNK_E;
    int end = min(base + CHUNK_E, NE);
    for (int i = base + threadIdx.x; i < end; i += 256) {
        int d = dstA[i];
        if (d >= lo && d < hi) {
            int s = srcA[i];
            int pos = atomicAdd(&fill[d], 1);
            int2 m;
            m.x = s;
            m.y = __float_as_int(dinv[s]);
            meta[pos] = m;
        }
    }
}

// ---------------- compute kernels ----------------

// pe = RWPE @ W_rw + b_rw ; writes interleaved fp16 row: [hs = x+pe | pe]
__global__ void k_pe(const float* __restrict__ x, const float* __restrict__ rwpe,
                     const float* __restrict__ Wrw, const float* __restrict__ brw,
                     __half* __restrict__ outI) {
    __shared__ float Wl[PD * FD];
    __shared__ float rows[4 * PD];
    int t = threadIdx.x;
    int nodeBase = blockIdx.x * 4;
    for (int i = t; i < PD * FD; i += 256) Wl[i] = Wrw[i];
    if (t < 4 * PD) {
        int n = nodeBase + t / PD;
        rows[t] = (n < NN) ? rwpe[n * PD + (t % PD)] : 0.f;
    }
    __syncthreads();
    int f = t & 63, sl = t >> 6;
    int node = nodeBase + sl;
    if (node < NN) {
        float acc = brw[f];
        #pragma unroll
        for (int k = 0; k < PD; k++) acc += rows[sl * PD + k] * Wl[k * FD + f];
        outI[(size_t)node * 128 + f]      = __float2half_rn(x[node * FD + f] + acc);
        outI[(size_t)node * 128 + 64 + f] = __float2half_rn(acc);
    }
}

__device__ inline void acc8(float* acc, uint4 v, float w) {
    const __half2* h = reinterpret_cast<const __half2*>(&v);
    float2 f0 = __half22float2(h[0]);
    float2 f1 = __half22float2(h[1]);
    float2 f2 = __half22float2(h[2]);
    float2 f3 = __half22float2(h[3]);
    acc[0] += w * f0.x; acc[1] += w * f0.y;
    acc[2] += w * f1.x; acc[3] += w * f1.y;
    acc[4] += w * f2.x; acc[5] += w * f2.y;
    acc[6] += w * f3.x; acc[7] += w * f3.y;
}

__device__ inline void acc4(float* acc, uint2 v, float w) {
    const __half2* h = reinterpret_cast<const __half2*>(&v);
    float2 f0 = __half22float2(h[0]);
    float2 f1 = __half22float2(h[1]);
    acc[0] += w * f0.x; acc[1] += w * f0.y;
    acc[2] += w * f1.x; acc[3] += w * f1.y;
}

// Fused dual GCN conv on interleaved fp16 state rows [hs(64)|pe(64)].
// (round-9 structure: 256 threads, 16 slots x 16 lanes, shfl-meta, 8-load groups)
// FINAL additionally reduces BN stats (sum, sumsq per feature) into statsG.
template <bool FINAL>
__global__ __launch_bounds__(256) void k_dual(
    const __half* __restrict__ in,
    const float* __restrict__ dinv, const int* __restrict__ rowp,
    const int2* __restrict__ meta,
    const float* __restrict__ Wc, const float* __restrict__ bc,
    const float* __restrict__ Wp, const float* __restrict__ bp,
    __half* __restrict__ out, int write_pe,
    float* __restrict__ foutF, float* __restrict__ statsG)
{
    __shared__ float Wl[64 * 64];
    __shared__ float aggH[16 * 68];
    __shared__ float aggP[16 * 68];
    __shared__ float red1[FINAL ? 256 : 1];
    __shared__ float red2[FINAL ? 256 : 1];
    int t = threadIdx.x;

    // stage Wc
    {
        const float4* W4 = reinterpret_cast<const float4*>(Wc);
        float4* Wl4 = reinterpret_cast<float4*>(Wl);
        #pragma unroll
        for (int i = 0; i < 4; i++) Wl4[t + 256 * i] = W4[t + 256 * i];
    }

    int l = t & 15;            // lane within slot
    int sl = t >> 4;           // slot in block 0..15
    int ws = (t >> 4) & 3;     // slot within wave 0..3
    int node = blockIdx.x * 16 + sl;
    int e0 = rowp[node], e1 = rowp[node + 1];
    int cnt = e1 - e0;
    float dd = dinv[node];

    if (!FINAL) {
        const uint4* base = reinterpret_cast<const uint4*>(in);   // row = 16 uint4
        float acc[8] = {0, 0, 0, 0, 0, 0, 0, 0};
        for (int cb = 0; cb < cnt; cb += 16) {
            int midx = min(e0 + cb + l, NE - 1);
            int2 mreg = meta[midx];
            int rem = cnt - cb;                    // >= 1
            int src0 = __shfl(mreg.x, ws * 16, 64);   // first edge of chunk (valid)
            #pragma unroll
            for (int g = 0; g < 2; g++) {
                if (g == 1 && rem <= 8) break;     // slot-uniform branch
                int srcj[8]; float wj[8];
                #pragma unroll
                for (int jj = 0; jj < 8; jj++) {
                    int j = g * 8 + jj;
                    int sx = __shfl(mreg.x, ws * 16 + j, 64);
                    float ww = __int_as_float(__shfl(mreg.y, ws * 16 + j, 64));
                    bool valid = (j < rem);
                    srcj[jj] = valid ? sx : src0;  // padded loads hit L1 (same row)
                    wj[jj] = valid ? ww : 0.f;
                }
                uint4 v0 = base[(size_t)srcj[0] * 16 + l];
                uint4 v1 = base[(size_t)srcj[1] * 16 + l];
                uint4 v2 = base[(size_t)srcj[2] * 16 + l];
                uint4 v3 = base[(size_t)srcj[3] * 16 + l];
                uint4 v4 = base[(size_t)srcj[4] * 16 + l];
                uint4 v5 = base[(size_t)srcj[5] * 16 + l];
                uint4 v6 = base[(size_t)srcj[6] * 16 + l];
                uint4 v7 = base[(size_t)srcj[7] * 16 + l];
                acc8(acc, v0, wj[0]);
                acc8(acc, v1, wj[1]);
                acc8(acc, v2, wj[2]);
                acc8(acc, v3, wj[3]);
                acc8(acc, v4, wj[4]);
                acc8(acc, v5, wj[5]);
                acc8(acc, v6, wj[6]);
                acc8(acc, v7, wj[7]);
            }
        }
        float s[8];
        {
            uint4 sv = base[(size_t)node * 16 + l];
            const __half2* h = reinterpret_cast<const __half2*>(&sv);
            float2 f0 = __half22float2(h[0]);
            float2 f1 = __half22float2(h[1]);
            float2 f2 = __half22float2(h[2]);
            float2 f3 = __half22float2(h[3]);
            s[0] = f0.x; s[1] = f0.y; s[2] = f1.x; s[3] = f1.y;
            s[4] = f2.x; s[5] = f2.y; s[6] = f3.x; s[7] = f3.y;
        }
        float* dst = (l < 8) ? &aggH[sl * 68 + l * 8] : &aggP[sl * 68 + (l - 8) * 8];
        float4* d4 = reinterpret_cast<float4*>(dst);
        d4[0] = make_float4(dd * acc[0] + dd * dd * s[0],
                            dd * acc[1] + dd * dd * s[1],
                            dd * acc[2] + dd * dd * s[2],
                            dd * acc[3] + dd * dd * s[3]);
        d4[1] = make_float4(dd * acc[4] + dd * dd * s[4],
                            dd * acc[5] + dd * dd * s[5],
                            dd * acc[6] + dd * dd * s[6],
                            dd * acc[7] + dd * dd * s[7]);
    } else {
        const uint2* base2 = reinterpret_cast<const uint2*>(in);  // row = 32 uint2
        float acc[4] = {0, 0, 0, 0};
        for (int cb = 0; cb < cnt; cb += 16) {
            int midx = min(e0 + cb + l, NE - 1);
            int2 mreg = meta[midx];
            int rem = cnt - cb;
            int src0 = __shfl(mreg.x, ws * 16, 64);
            #pragma unroll
            for (int g = 0; g < 2; g++) {
                if (g == 1 && rem <= 8) break;
                int srcj[8]; float wj[8];
                #pragma unroll
                for (int jj = 0; jj < 8; jj++) {
                    int j = g * 8 + jj;
                    int sx = __shfl(mreg.x, ws * 16 + j, 64);
                    float ww = __int_as_float(__shfl(mreg.y, ws * 16 + j, 64));
                    bool valid = (j < rem);
                    srcj[jj] = valid ? sx : src0;
                    wj[jj] = valid ? ww : 0.f;
                }
                uint2 v0 = base2[(size_t)srcj[0] * 32 + l];
                uint2 v1 = base2[(size_t)srcj[1] * 32 + l];
                uint2 v2 = base2[(size_t)srcj[2] * 32 + l];
                uint2 v3 = base2[(size_t)srcj[3] * 32 + l];
                uint2 v4 = base2[(size_t)srcj[4] * 32 + l];
                uint2 v5 = base2[(size_t)srcj[5] * 32 + l];
                uint2 v6 = base2[(size_t)srcj[6] * 32 + l];
                uint2 v7 = base2[(size_t)srcj[7] * 32 + l];
                acc4(acc, v0, wj[0]);
                acc4(acc, v1, wj[1]);
                acc4(acc, v2, wj[2]);
                acc4(acc, v3, wj[3]);
                acc4(acc, v4, wj[4]);
                acc4(acc, v5, wj[5]);
                acc4(acc, v6, wj[6]);
                acc4(acc, v7, wj[7]);
            }
        }
        float s[4];
        {
            uint2 sv = base2[(size_t)node * 32 + l];
            const __half2* h = reinterpret_cast<const __half2*>(&sv);
            float2 f0 = __half22float2(h[0]);
            float2 f1 = __half22float2(h[1]);
            s[0] = f0.x; s[1] = f0.y; s[2] = f1.x; s[3] = f1.y;
        }
        float4* d4 = reinterpret_cast<float4*>(&aggH[sl * 68 + l * 4]);
        d4[0] = make_float4(dd * acc[0] + dd * dd * s[0],
                            dd * acc[1] + dd * dd * s[1],
                            dd * acc[2] + dd * dd * s[2],
                            dd * acc[3] + dd * dd * s[3]);
    }
    __syncthreads();

    // GEMM-h: oh = aggH @ Wc + bc
    int c = t & 15;
    int sl2 = t >> 4;
    int onode = blockIdx.x * 16 + sl2;
    float4 oh = *reinterpret_cast<const float4*>(bc + c * 4);
    {
        const float* arow = &aggH[sl2 * 68];
        #pragma unroll 16
        for (int k = 0; k < 64; k++) {
            float av = arow[k];
            float4 wv = *reinterpret_cast<const float4*>(&Wl[k * 64 + c * 4]);
            oh.x += av * wv.x; oh.y += av * wv.y; oh.z += av * wv.z; oh.w += av * wv.w;
        }
    }
    if (FINAL) {
        *reinterpret_cast<float4*>(foutF + (size_t)onode * 64 + c * 4) = oh;
        // BN-stats partial reduce: sum & sumsq per feature over this block's 16 nodes
        float s1v[4] = {oh.x, oh.y, oh.z, oh.w};
        float s2v[4] = {oh.x * oh.x, oh.y * oh.y, oh.z * oh.z, oh.w * oh.w};
        #pragma unroll
        for (int j = 0; j < 4; j++) {
            s1v[j] += __shfl_xor(s1v[j], 16, 64);
            s2v[j] += __shfl_xor(s2v[j], 16, 64);
            s1v[j] += __shfl_xor(s1v[j], 32, 64);
            s2v[j] += __shfl_xor(s2v[j], 32, 64);
        }
        int wv = t >> 6;   // wave 0..3
        if ((t & 63) < 16) {
            #pragma unroll
            for (int j = 0; j < 4; j++) {
                red1[wv * 64 + c * 4 + j] = s1v[j];
                red2[wv * 64 + c * 4 + j] = s2v[j];
            }
        }
        __syncthreads();
        if (t < 64) {
            float a = red1[t] + red1[64 + t] + red1[128 + t] + red1[192 + t];
            float b = red2[t] + red2[64 + t] + red2[128 + t] + red2[192 + t];
            atomicAdd(&statsG[t], a);
            atomicAdd(&statsG[64 + t], b);
        }
        return;
    }
    oh.x = fmaxf(oh.x, 0.f); oh.y = fmaxf(oh.y, 0.f);
    oh.z = fmaxf(oh.z, 0.f); oh.w = fmaxf(oh.w, 0.f);

    __syncthreads();   // everyone done reading Wc
    // restage Wp over Wl
    {
        const float4* W4 = reinterpret_cast<const float4*>(Wp);
        float4* Wl4 = reinterpret_cast<float4*>(Wl);
        #pragma unroll
        for (int i = 0; i < 4; i++) Wl4[t + 256 * i] = W4[t + 256 * i];
    }
    __syncthreads();

    // GEMM-p: op = relu(aggP @ Wp + bp)
    float4 op = *reinterpret_cast<const float4*>(bp + c * 4);
    {
        const float* arow = &aggP[sl2 * 68];
        #pragma unroll 16
        for (int k = 0; k < 64; k++) {
            float av = arow[k];
            float4 wv = *reinterpret_cast<const float4*>(&Wl[k * 64 + c * 4]);
            op.x += av * wv.x; op.y += av * wv.y; op.z += av * wv.z; op.w += av * wv.w;
        }
    }
    op.x = fmaxf(op.x, 0.f); op.y = fmaxf(op.y, 0.f);
    op.z = fmaxf(op.z, 0.f); op.w = fmaxf(op.w, 0.f);

    uint2* out2 = reinterpret_cast<uint2*>(out);
    {
        __half2 a = __floats2half2_rn(oh.x + op.x, oh.y + op.y);
        __half2 b = __floats2half2_rn(oh.z + op.z, oh.w + op.w);
        uint2 u;
        u.x = *reinterpret_cast<unsigned int*>(&a);
        u.y = *reinterpret_cast<unsigned int*>(&b);
        out2[(size_t)onode * 32 + c] = u;
    }
    if (write_pe) {
        __half2 a = __floats2half2_rn(op.x, op.y);
        __half2 b = __floats2half2_rn(op.z, op.w);
        uint2 u;
        u.x = *reinterpret_cast<unsigned int*>(&a);
        u.y = *reinterpret_cast<unsigned int*>(&b);
        out2[(size_t)onode * 32 + 16 + c] = u;
    }
}

// ---------------- batchnorm + pool (fused finalize) ----------------

// 256 threads: f = t&63, 4 node stripes; mu/rstd computed from raw stats per block
__global__ void k_pool(const float* __restrict__ h, const float* __restrict__ stats,
                       const float* __restrict__ gamma, const float* __restrict__ beta,
                       const int* __restrict__ ptr, float* __restrict__ out) {
    __shared__ float red[256];
    int g = blockIdx.x;
    int t = threadIdx.x;
    int f = t & 63, stripe = t >> 6;
    float mu = stats[f] / (float)NN;
    float var = stats[64 + f] / (float)NN - mu * mu;
    float rstd = rsqrtf(var + 1e-5f);
    float ga = gamma[f], be = beta[f];
    int s = ptr[g], e = ptr[g + 1];
    float acc = 0.f;
    for (int n = s + stripe; n < e; n += 4) {
        float v = (h[(size_t)n * 64 + f] - mu) * rstd * ga + be;
        acc += fmaxf(v, 0.f);
    }
    red[t] = acc;
    __syncthreads();
    if (t < 64)
        out[g * 64 + f] = (red[t] + red[t + 64] + red[t + 128] + red[t + 192]) / (float)(e - s);
}

// ---------------- launch ----------------

extern "C" void kernel_launch(void* const* d_in, const int* in_sizes, int n_in,
                              void* d_out, int out_size, void* d_ws, size_t ws_size,
                              hipStream_t stream) {
    const float* x    = (const float*)d_in[0];
    const float* rwpe = (const float*)d_in[1];
    const float* Wrw  = (const float*)d_in[2];
    const float* brw  = (const float*)d_in[3];
    const float *Wc[5], *bc[5], *Wp[5], *bp[5];
    for (int i = 0; i < 5; i++) {
        Wc[i] = (const float*)d_in[4 + 4 * i];
        bc[i] = (const float*)d_in[5 + 4 * i];
        Wp[i] = (const float*)d_in[6 + 4 * i];
        bp[i] = (const float*)d_in[7 + 4 * i];
    }
    const float* gamma = (const float*)d_in[24];
    const float* beta  = (const float*)d_in[25];
    const int* ei  = (const int*)d_in[26];
    const int* ptr = (const int*)d_in[27];
    float* out = (float*)d_out;

    char* wsp = (char*)d_ws;
    auto alloc = [&](size_t bytes) { void* p = (void*)wsp; wsp += ((bytes + 255) / 256) * 256; return p; };
    int*    deg   = (int*)alloc(NN * 4);
    int*    rowp  = (int*)alloc((NN + 1) * 4);
    int*    fill  = (int*)alloc(NN * 4);
    int2*   meta  = (int2*)alloc((size_t)NE * 8);
    float*  dinv  = (float*)alloc(NN * 4);
    __half* bufP  = (__half*)alloc((size_t)NN * 128 * 2);   // interleaved [hs|pe]
    __half* bufQ  = (__half*)alloc((size_t)NN * 128 * 2);
    float*  bufF  = (float*)alloc((size_t)NN * 64 * 4);     // final conv5 out fp32
    float*  stats = (float*)alloc(512);
    int*    bsum  = (int*)alloc(256 * 4);

    hipMemsetAsync(deg, 0, NN * 4, stream);
    hipMemsetAsync(stats, 0, 512, stream);

    const int* srcA = ei;
    const int* dstA = ei + NE;

    dim3 b256(256);
    int gN = (NN + 255) / 256;                        // 196
    int gNode16 = NN / 16;                            // 3125 (exact)
    int gFill = ((NE + CHUNK_E - 1) / CHUNK_E) * 8;   // 391 * 8 = 3128

    k_deg_xcd<<<gFill, b256, 0, stream>>>(dstA, deg);
    k_scan1<<<gN, b256, 0, stream>>>(deg, rowp, bsum, dinv);
    k_scan3<<<gN, b256, 0, stream>>>(rowp, bsum, fill, gN);
    k_csr_fill_xcd<<<gFill, b256, 0, stream>>>(srcA, dstA, dinv, fill, meta);

    k_pe<<<(NN + 3) / 4, b256, 0, stream>>>(x, rwpe, Wrw, brw, bufP);

    // K0..K3: dual convs; K3 skips dead pe write
    k_dual<false><<<gNode16, b256, 0, stream>>>(
        bufP, dinv, rowp, meta, Wc[0], bc[0], Wp[0], bp[0], bufQ, 1, nullptr, nullptr);
    k_dual<false><<<gNode16, b256, 0, stream>>>(
        bufQ, dinv, rowp, meta, Wc[1], bc[1], Wp[1], bp[1], bufP, 1, nullptr, nullptr);
    k_dual<false><<<gNode16, b256, 0, stream>>>(
        bufP, dinv, rowp, meta, Wc[2], bc[2], Wp[2], bp[2], bufQ, 1, nullptr, nullptr);
    k_dual<false><<<gNode16, b256, 0, stream>>>(
        bufQ, dinv, rowp, meta, Wc[3], bc[3], Wp[3], bp[3], bufP, 0, nullptr, nullptr);
    // K4: final conv (hs only) -> fp32, with fused BN-stats reduction
    k_dual<true><<<gNode16, b256, 0, stream>>>(
        bufP, dinv, rowp, meta, Wc[4], bc[4], nullptr, nullptr, nullptr, 0, bufF, stats);

    k_pool<<<NG, b256, 0, stream>>>(bufF, stats, gamma, beta, ptr, out);
}

// Round 12
// 305.068 us; speedup vs baseline: 1.4761x; 1.1930x over previous
//
#include <hip/hip_runtime.h>
#include <hip/hip_fp16.h>

#define NN 50000
#define NE 800000
#define FD 64
#define PD 20
#define NG 500
#define NXCD 8
#define DRANGE 6250            // NN / NXCD
#define CHUNK_E 2048

// ---------------- setup kernels ----------------

__global__ void k_deg_xcd(const int* __restrict__ dstA, int* __restrict__ deg) {
    int xcd = blockIdx.x & 7;
    int chunk = blockIdx.x >> 3;
    int lo = xcd * DRANGE;
    int hi = lo + DRANGE;
    int base = chunk * CHUNK_E;
    int end = min(base + CHUNK_E, NE);
    for (int i = base + threadIdx.x; i < end; i += 256) {
        int d = dstA[i];
        if (d >= lo && d < hi) atomicAdd(&deg[d], 1);
    }
}

// scan1 + dinv fused
__global__ void k_scan1(const int* __restrict__ deg, int* __restrict__ rowp,
                        int* __restrict__ bsum, float* __restrict__ dinv) {
    __shared__ int lds[256];
    int t = threadIdx.x;
    int idx = blockIdx.x * 256 + t;
    int v = (idx < NN) ? deg[idx] : 0;
    if (idx < NN) dinv[idx] = rsqrtf((float)v + 1.0f);
    lds[t] = v;
    __syncthreads();
    for (int off = 1; off < 256; off <<= 1) {
        int add = (t >= off) ? lds[t - off] : 0;
        __syncthreads();
        lds[t] += add;
        __syncthreads();
    }
    if (idx < NN) rowp[idx + 1] = lds[t];
    if (t == 255) bsum[blockIdx.x] = lds[255];
}

// finalize rowp AND fill[] ; each block redundantly scans bsum in LDS (no scan2 kernel)
__global__ void k_scan3(int* __restrict__ rowp, const int* __restrict__ bsum,
                        int* __restrict__ fill, int nB) {
    __shared__ int lds[256];
    int t = threadIdx.x;
    lds[t] = (t < nB) ? bsum[t] : 0;
    __syncthreads();
    for (int off = 1; off < 256; off <<= 1) {
        int add = (t >= off) ? lds[t - off] : 0;
        __syncthreads();
        lds[t] += add;
        __syncthreads();
    }
    int addv = (blockIdx.x > 0) ? lds[blockIdx.x - 1] : 0;
    int idx = blockIdx.x * 256 + t;
    if (idx == 0) { rowp[0] = 0; fill[0] = 0; }
    if (idx < NN) {
        int v = rowp[idx + 1] + addv;
        rowp[idx + 1] = v;
        if (idx + 1 < NN) fill[idx + 1] = v;
    }
}

__global__ void k_csr_fill_xcd(const int* __restrict__ srcA, const int* __restrict__ dstA,
                               const float* __restrict__ dinv,
                               int* __restrict__ fill, int2* __restrict__ meta) {
    int xcd = blockIdx.x & 7;
    int chunk = blockIdx.x >> 3;
    int lo = xcd * DRANGE;
    int hi = lo + DRANGE;
    int base = chunk * CHUNK_E;
    int end = min(base + CHUNK_E, NE);
    for (int i = base + threadIdx.x; i < end; i += 256) {
        int d = dstA[i];
        if (d >= lo && d < hi) {
            int s = srcA[i];
            int pos = atomicAdd(&fill[d], 1);
            int2 m;
            m.x = s;
            m.y = __float_as_int(dinv[s]);
            meta[pos] = m;
        }
    }
}

// ---------------- compute kernels ----------------

// pe = RWPE @ W_rw + b_rw ; writes interleaved fp16 row: [hs = x+pe | pe]
__global__ void k_pe(const float* __restrict__ x, const float* __restrict__ rwpe,
                     const float* __restrict__ Wrw, const float* __restrict__ brw,
                     __half* __restrict__ outI) {
    __shared__ float Wl[PD * FD];
    __shared__ float rows[4 * PD];
    int t = threadIdx.x;
    int nodeBase = blockIdx.x * 4;
    for (int i = t; i < PD * FD; i += 256) Wl[i] = Wrw[i];
    if (t < 4 * PD) {
        int n = nodeBase + t / PD;
        rows[t] = (n < NN) ? rwpe[n * PD + (t % PD)] : 0.f;
    }
    __syncthreads();
    int f = t & 63, sl = t >> 6;
    int node = nodeBase + sl;
    if (node < NN) {
        float acc = brw[f];
        #pragma unroll
        for (int k = 0; k < PD; k++) acc += rows[sl * PD + k] * Wl[k * FD + f];
        outI[(size_t)node * 128 + f]      = __float2half_rn(x[node * FD + f] + acc);
        outI[(size_t)node * 128 + 64 + f] = __float2half_rn(acc);
    }
}

__device__ inline void acc8(float* acc, uint4 v, float w) {
    const __half2* h = reinterpret_cast<const __half2*>(&v);
    float2 f0 = __half22float2(h[0]);
    float2 f1 = __half22float2(h[1]);
    float2 f2 = __half22float2(h[2]);
    float2 f3 = __half22float2(h[3]);
    acc[0] += w * f0.x; acc[1] += w * f0.y;
    acc[2] += w * f1.x; acc[3] += w * f1.y;
    acc[4] += w * f2.x; acc[5] += w * f2.y;
    acc[6] += w * f3.x; acc[7] += w * f3.y;
}

__device__ inline void acc4(float* acc, uint2 v, float w) {
    const __half2* h = reinterpret_cast<const __half2*>(&v);
    float2 f0 = __half22float2(h[0]);
    float2 f1 = __half22float2(h[1]);
    acc[0] += w * f0.x; acc[1] += w * f0.y;
    acc[2] += w * f1.x; acc[3] += w * f1.y;
}

// Fused dual GCN conv on interleaved fp16 state rows [hs(64)|pe(64)].
// (round-9 structure: 256 threads, 16 slots x 16 lanes, shfl-meta, 8-load groups)
// FINAL additionally reduces BN stats into per-XCD slots of statsG (8 x 128 floats)
// -- atomics stay XCD-local, no cross-XCD line bouncing (round-11 lesson).
template <bool FINAL>
__global__ __launch_bounds__(256) void k_dual(
    const __half* __restrict__ in,
    const float* __restrict__ dinv, const int* __restrict__ rowp,
    const int2* __restrict__ meta,
    const float* __restrict__ Wc, const float* __restrict__ bc,
    const float* __restrict__ Wp, const float* __restrict__ bp,
    __half* __restrict__ out, int write_pe,
    float* __restrict__ foutF, float* __restrict__ statsG)
{
    __shared__ float Wl[64 * 64];
    __shared__ float aggH[16 * 68];
    __shared__ float aggP[16 * 68];
    __shared__ float red1[FINAL ? 256 : 1];
    __shared__ float red2[FINAL ? 256 : 1];
    int t = threadIdx.x;

    // stage Wc
    {
        const float4* W4 = reinterpret_cast<const float4*>(Wc);
        float4* Wl4 = reinterpret_cast<float4*>(Wl);
        #pragma unroll
        for (int i = 0; i < 4; i++) Wl4[t + 256 * i] = W4[t + 256 * i];
    }

    int l = t & 15;            // lane within slot
    int sl = t >> 4;           // slot in block 0..15
    int ws = (t >> 4) & 3;     // slot within wave 0..3
    int node = blockIdx.x * 16 + sl;
    int e0 = rowp[node], e1 = rowp[node + 1];
    int cnt = e1 - e0;
    float dd = dinv[node];

    if (!FINAL) {
        const uint4* base = reinterpret_cast<const uint4*>(in);   // row = 16 uint4
        float acc[8] = {0, 0, 0, 0, 0, 0, 0, 0};
        for (int cb = 0; cb < cnt; cb += 16) {
            int midx = min(e0 + cb + l, NE - 1);
            int2 mreg = meta[midx];
            int rem = cnt - cb;                    // >= 1
            int src0 = __shfl(mreg.x, ws * 16, 64);   // first edge of chunk (valid)
            #pragma unroll
            for (int g = 0; g < 2; g++) {
                if (g == 1 && rem <= 8) break;     // slot-uniform branch
                int srcj[8]; float wj[8];
                #pragma unroll
                for (int jj = 0; jj < 8; jj++) {
                    int j = g * 8 + jj;
                    int sx = __shfl(mreg.x, ws * 16 + j, 64);
                    float ww = __int_as_float(__shfl(mreg.y, ws * 16 + j, 64));
                    bool valid = (j < rem);
                    srcj[jj] = valid ? sx : src0;  // padded loads hit L1 (same row)
                    wj[jj] = valid ? ww : 0.f;
                }
                uint4 v0 = base[(size_t)srcj[0] * 16 + l];
                uint4 v1 = base[(size_t)srcj[1] * 16 + l];
                uint4 v2 = base[(size_t)srcj[2] * 16 + l];
                uint4 v3 = base[(size_t)srcj[3] * 16 + l];
                uint4 v4 = base[(size_t)srcj[4] * 16 + l];
                uint4 v5 = base[(size_t)srcj[5] * 16 + l];
                uint4 v6 = base[(size_t)srcj[6] * 16 + l];
                uint4 v7 = base[(size_t)srcj[7] * 16 + l];
                acc8(acc, v0, wj[0]);
                acc8(acc, v1, wj[1]);
                acc8(acc, v2, wj[2]);
                acc8(acc, v3, wj[3]);
                acc8(acc, v4, wj[4]);
                acc8(acc, v5, wj[5]);
                acc8(acc, v6, wj[6]);
                acc8(acc, v7, wj[7]);
            }
        }
        float s[8];
        {
            uint4 sv = base[(size_t)node * 16 + l];
            const __half2* h = reinterpret_cast<const __half2*>(&sv);
            float2 f0 = __half22float2(h[0]);
            float2 f1 = __half22float2(h[1]);
            float2 f2 = __half22float2(h[2]);
            float2 f3 = __half22float2(h[3]);
            s[0] = f0.x; s[1] = f0.y; s[2] = f1.x; s[3] = f1.y;
            s[4] = f2.x; s[5] = f2.y; s[6] = f3.x; s[7] = f3.y;
        }
        float* dst = (l < 8) ? &aggH[sl * 68 + l * 8] : &aggP[sl * 68 + (l - 8) * 8];
        float4* d4 = reinterpret_cast<float4*>(dst);
        d4[0] = make_float4(dd * acc[0] + dd * dd * s[0],
                            dd * acc[1] + dd * dd * s[1],
                            dd * acc[2] + dd * dd * s[2],
                            dd * acc[3] + dd * dd * s[3]);
        d4[1] = make_float4(dd * acc[4] + dd * dd * s[4],
                            dd * acc[5] + dd * dd * s[5],
                            dd * acc[6] + dd * dd * s[6],
                            dd * acc[7] + dd * dd * s[7]);
    } else {
        const uint2* base2 = reinterpret_cast<const uint2*>(in);  // row = 32 uint2
        float acc[4] = {0, 0, 0, 0};
        for (int cb = 0; cb < cnt; cb += 16) {
            int midx = min(e0 + cb + l, NE - 1);
            int2 mreg = meta[midx];
            int rem = cnt - cb;
            int src0 = __shfl(mreg.x, ws * 16, 64);
            #pragma unroll
            for (int g = 0; g < 2; g++) {
                if (g == 1 && rem <= 8) break;
                int srcj[8]; float wj[8];
                #pragma unroll
                for (int jj = 0; jj < 8; jj++) {
                    int j = g * 8 + jj;
                    int sx = __shfl(mreg.x, ws * 16 + j, 64);
                    float ww = __int_as_float(__shfl(mreg.y, ws * 16 + j, 64));
                    bool valid = (j < rem);
                    srcj[jj] = valid ? sx : src0;
                    wj[jj] = valid ? ww : 0.f;
                }
                uint2 v0 = base2[(size_t)srcj[0] * 32 + l];
                uint2 v1 = base2[(size_t)srcj[1] * 32 + l];
                uint2 v2 = base2[(size_t)srcj[2] * 32 + l];
                uint2 v3 = base2[(size_t)srcj[3] * 32 + l];
                uint2 v4 = base2[(size_t)srcj[4] * 32 + l];
                uint2 v5 = base2[(size_t)srcj[5] * 32 + l];
                uint2 v6 = base2[(size_t)srcj[6] * 32 + l];
                uint2 v7 = base2[(size_t)srcj[7] * 32 + l];
                acc4(acc, v0, wj[0]);
                acc4(acc, v1, wj[1]);
                acc4(acc, v2, wj[2]);
                acc4(acc, v3, wj[3]);
                acc4(acc, v4, wj[4]);
                acc4(acc, v5, wj[5]);
                acc4(acc, v6, wj[6]);
                acc4(acc, v7, wj[7]);
            }
        }
        float s[4];
        {
            uint2 sv = base2[(size_t)node * 32 + l];
            const __half2* h = reinterpret_cast<const __half2*>(&sv);
            float2 f0 = __half22float2(h[0]);
            float2 f1 = __half22float2(h[1]);
            s[0] = f0.x; s[1] = f0.y; s[2] = f1.x; s[3] = f1.y;
        }
        float4* d4 = reinterpret_cast<float4*>(&aggH[sl * 68 + l * 4]);
        d4[0] = make_float4(dd * acc[0] + dd * dd * s[0],
                            dd * acc[1] + dd * dd * s[1],
                            dd * acc[2] + dd * dd * s[2],
                            dd * acc[3] + dd * dd * s[3]);
    }
    __syncthreads();

    // GEMM-h: oh = aggH @ Wc + bc
    int c = t & 15;
    int sl2 = t >> 4;
    int onode = blockIdx.x * 16 + sl2;
    float4 oh = *reinterpret_cast<const float4*>(bc + c * 4);
    {
        const float* arow = &aggH[sl2 * 68];
        #pragma unroll 16
        for (int k = 0; k < 64; k++) {
            float av = arow[k];
            float4 wv = *reinterpret_cast<const float4*>(&Wl[k * 64 + c * 4]);
            oh.x += av * wv.x; oh.y += av * wv.y; oh.z += av * wv.z; oh.w += av * wv.w;
        }
    }
    if (FINAL) {
        *reinterpret_cast<float4*>(foutF + (size_t)onode * 64 + c * 4) = oh;
        // BN-stats partial reduce over this block's 16 nodes
        float s1v[4] = {oh.x, oh.y, oh.z, oh.w};
        float s2v[4] = {oh.x * oh.x, oh.y * oh.y, oh.z * oh.z, oh.w * oh.w};
        #pragma unroll
        for (int j = 0; j < 4; j++) {
            s1v[j] += __shfl_xor(s1v[j], 16, 64);
            s2v[j] += __shfl_xor(s2v[j], 16, 64);
            s1v[j] += __shfl_xor(s1v[j], 32, 64);
            s2v[j] += __shfl_xor(s2v[j], 32, 64);
        }
        int wv = t >> 6;   // wave 0..3
        if ((t & 63) < 16) {
            #pragma unroll
            for (int j = 0; j < 4; j++) {
                red1[wv * 64 + c * 4 + j] = s1v[j];
                red2[wv * 64 + c * 4 + j] = s2v[j];
            }
        }
        __syncthreads();
        if (t < 64) {
            float a = red1[t] + red1[64 + t] + red1[128 + t] + red1[192 + t];
            float b = red2[t] + red2[64 + t] + red2[128 + t] + red2[192 + t];
            float* slot = statsG + (blockIdx.x & 7) * 128;   // XCD-local slot
            atomicAdd(&slot[t], a);
            atomicAdd(&slot[64 + t], b);
        }
        return;
    }
    oh.x = fmaxf(oh.x, 0.f); oh.y = fmaxf(oh.y, 0.f);
    oh.z = fmaxf(oh.z, 0.f); oh.w = fmaxf(oh.w, 0.f);

    __syncthreads();   // everyone done reading Wc
    // restage Wp over Wl
    {
        const float4* W4 = reinterpret_cast<const float4*>(Wp);
        float4* Wl4 = reinterpret_cast<float4*>(Wl);
        #pragma unroll
        for (int i = 0; i < 4; i++) Wl4[t + 256 * i] = W4[t + 256 * i];
    }
    __syncthreads();

    // GEMM-p: op = relu(aggP @ Wp + bp)
    float4 op = *reinterpret_cast<const float4*>(bp + c * 4);
    {
        const float* arow = &aggP[sl2 * 68];
        #pragma unroll 16
        for (int k = 0; k < 64; k++) {
            float av = arow[k];
            float4 wv = *reinterpret_cast<const float4*>(&Wl[k * 64 + c * 4]);
            op.x += av * wv.x; op.y += av * wv.y; op.z += av * wv.z; op.w += av * wv.w;
        }
    }
    op.x = fmaxf(op.x, 0.f); op.y = fmaxf(op.y, 0.f);
    op.z = fmaxf(op.z, 0.f); op.w = fmaxf(op.w, 0.f);

    uint2* out2 = reinterpret_cast<uint2*>(out);
    {
        __half2 a = __floats2half2_rn(oh.x + op.x, oh.y + op.y);
        __half2 b = __floats2half2_rn(oh.z + op.z, oh.w + op.w);
        uint2 u;
        u.x = *reinterpret_cast<unsigned int*>(&a);
        u.y = *reinterpret_cast<unsigned int*>(&b);
        out2[(size_t)onode * 32 + c] = u;
    }
    if (write_pe) {
        __half2 a = __floats2half2_rn(op.x, op.y);
        __half2 b = __floats2half2_rn(op.z, op.w);
        uint2 u;
        u.x = *reinterpret_cast<unsigned int*>(&a);
        u.y = *reinterpret_cast<unsigned int*>(&b);
        out2[(size_t)onode * 32 + 16 + c] = u;
    }
}

// ---------------- batchnorm + pool (fused finalize) ----------------

// 256 threads: f = t&63, 4 node stripes; mu/rstd from the 8 per-XCD partials
__global__ void k_pool(const float* __restrict__ stats8, const float* __restrict__ h,
                       const float* __restrict__ gamma, const float* __restrict__ beta,
                       const int* __restrict__ ptr, float* __restrict__ out) {
    __shared__ float red[256];
    int g = blockIdx.x;
    int t = threadIdx.x;
    int f = t & 63, stripe = t >> 6;
    float s1 = 0.f, s2 = 0.f;
    #pragma unroll
    for (int p = 0; p < 8; p++) {
        s1 += stats8[p * 128 + f];
        s2 += stats8[p * 128 + 64 + f];
    }
    float mu = s1 / (float)NN;
    float var = s2 / (float)NN - mu * mu;
    float rstd = rsqrtf(var + 1e-5f);
    float ga = gamma[f], be = beta[f];
    int s = ptr[g], e = ptr[g + 1];
    float acc = 0.f;
    for (int n = s + stripe; n < e; n += 4) {
        float v = (h[(size_t)n * 64 + f] - mu) * rstd * ga + be;
        acc += fmaxf(v, 0.f);
    }
    red[t] = acc;
    __syncthreads();
    if (t < 64)
        out[g * 64 + f] = (red[t] + red[t + 64] + red[t + 128] + red[t + 192]) / (float)(e - s);
}

// ---------------- launch ----------------

extern "C" void kernel_launch(void* const* d_in, const int* in_sizes, int n_in,
                              void* d_out, int out_size, void* d_ws, size_t ws_size,
                              hipStream_t stream) {
    const float* x    = (const float*)d_in[0];
    const float* rwpe = (const float*)d_in[1];
    const float* Wrw  = (const float*)d_in[2];
    const float* brw  = (const float*)d_in[3];
    const float *Wc[5], *bc[5], *Wp[5], *bp[5];
    for (int i = 0; i < 5; i++) {
        Wc[i] = (const float*)d_in[4 + 4 * i];
        bc[i] = (const float*)d_in[5 + 4 * i];
        Wp[i] = (const float*)d_in[6 + 4 * i];
        bp[i] = (const float*)d_in[7 + 4 * i];
    }
    const float* gamma = (const float*)d_in[24];
    const float* beta  = (const float*)d_in[25];
    const int* ei  = (const int*)d_in[26];
    const int* ptr = (const int*)d_in[27];
    float* out = (float*)d_out;

    char* wsp = (char*)d_ws;
    auto alloc = [&](size_t bytes) { void* p = (void*)wsp; wsp += ((bytes + 255) / 256) * 256; return p; };
    int*    deg   = (int*)alloc(NN * 4);
    int*    rowp  = (int*)alloc((NN + 1) * 4);
    int*    fill  = (int*)alloc(NN * 4);
    int2*   meta  = (int2*)alloc((size_t)NE * 8);
    float*  dinv  = (float*)alloc(NN * 4);
    __half* bufP  = (__half*)alloc((size_t)NN * 128 * 2);   // interleaved [hs|pe]
    __half* bufQ  = (__half*)alloc((size_t)NN * 128 * 2);
    float*  bufF  = (float*)alloc((size_t)NN * 64 * 4);     // final conv5 out fp32
    float*  stats = (float*)alloc(8 * 128 * 4);             // 8 per-XCD slots
    int*    bsum  = (int*)alloc(256 * 4);

    hipMemsetAsync(deg, 0, NN * 4, stream);
    hipMemsetAsync(stats, 0, 8 * 128 * 4, stream);

    const int* srcA = ei;
    const int* dstA = ei + NE;

    dim3 b256(256);
    int gN = (NN + 255) / 256;                        // 196
    int gNode16 = NN / 16;                            // 3125 (exact)
    int gFill = ((NE + CHUNK_E - 1) / CHUNK_E) * 8;   // 391 * 8 = 3128

    k_deg_xcd<<<gFill, b256, 0, stream>>>(dstA, deg);
    k_scan1<<<gN, b256, 0, stream>>>(deg, rowp, bsum, dinv);
    k_scan3<<<gN, b256, 0, stream>>>(rowp, bsum, fill, gN);
    k_csr_fill_xcd<<<gFill, b256, 0, stream>>>(srcA, dstA, dinv, fill, meta);

    k_pe<<<(NN + 3) / 4, b256, 0, stream>>>(x, rwpe, Wrw, brw, bufP);

    // K0..K3: dual convs; K3 skips dead pe write
    k_dual<false><<<gNode16, b256, 0, stream>>>(
        bufP, dinv, rowp, meta, Wc[0], bc[0], Wp[0], bp[0], bufQ, 1, nullptr, nullptr);
    k_dual<false><<<gNode16, b256, 0, stream>>>(
        bufQ, dinv, rowp, meta, Wc[1], bc[1], Wp[1], bp[1], bufP, 1, nullptr, nullptr);
    k_dual<false><<<gNode16, b256, 0, stream>>>(
        bufP, dinv, rowp, meta, Wc[2], bc[2], Wp[2], bp[2], bufQ, 1, nullptr, nullptr);
    k_dual<false><<<gNode16, b256, 0, stream>>>(
        bufQ, dinv, rowp, meta, Wc[3], bc[3], Wp[3], bp[3], bufP, 0, nullptr, nullptr);
    // K4: final conv (hs only) -> fp32, with fused per-XCD BN-stats reduction
    k_dual<true><<<gNode16, b256, 0, stream>>>(
        bufP, dinv, rowp, meta, Wc[4], bc[4], nullptr, nullptr, nullptr, 0, bufF, stats);

    k_pool<<<NG, b256, 0, stream>>>(stats, bufF, gamma, beta, ptr, out);
}